// Round 10
// baseline (27.351 us; speedup 1.0000x reference)
//
#include <hip/hip_runtime.h>

#define SLEN   300
#define PT     20
#define STEP   4
#define MAXD   2
#define NBANDS 2
#define NS     30
#define NGAL   8
#define BATCH  8
#define N1     71            // (300-20)/4+1
#define NPT    (N1*N1)       // 5041
#define NSUB   (BATCH*NPT)   // 40328

// ---- output layout (flat float32, in reference return order) ----
#define OFF_LOCS 32262400
#define OFF_GAL  32423712
#define OFF_FLUX 33068960
#define OFF_N    33230272
#define OFF_ISON 33270600

// Single-round grid, (b, i, band) decomposition: 1136 tile blocks + 158
// catalog blocks = 1294 < 2048 resident capacity. Per-block unique read
// footprint = 1 band x 20 rows x 300 cols x 4B = 24 KB < 32 KB L1 ->
// strip is L1-resident after first touch (R9's 51 KB half-row strip wasn't).
#define TILE_BLOCKS (BATCH * N1 * NBANDS)     // 1136 = 8 * 142
#define CAT_BLOCKS  ((NSUB + 255) / 256)      // 158
#define CHUNK (TILE_BLOCKS / 8)               // 142 blocks per XCD (= 1 batch)

typedef float vf4 __attribute__((ext_vector_type(4)));

__global__ __launch_bounds__(256) void fused_kernel(
    const float* __restrict__ img,
    const float* __restrict__ locs,
    const float* __restrict__ gal,
    const float* __restrict__ flux,
    float* __restrict__ out)
{
    const int bid = blockIdx.x;
    const int tid = threadIdx.x;

    if (bid < TILE_BLOCKS) {
        // ---------------- patch extraction (direct L1-resident reads) ------
        // XCD swizzle: 1136 = 8*142; XCD k gets chunk == batch k (720 KB L2).
        const int wg = (bid & 7) * CHUNK + (bid >> 3);
        const int c  = wg & 1;               // band
        const int bi = wg >> 1;
        const int i  = bi % N1;
        const int b  = bi / N1;

        const int sub0 = b * NPT + i * N1;
        // band-c chunk of each patch: 100 f4 at offset sub*200 + c*100
        vf4* base = reinterpret_cast<vf4*>(out) + (size_t)sub0 * 200 + c * 100;
        const float* imb = img
            + (size_t)((b * NBANDS + c) * SLEN + i * STEP) * SLEN;

        // w == jj*100 + rr*5 + q  over all 71 patches of this (b,i,band)
        const int tot = N1 * 100;   // 7100
        for (int w = tid; w < tot; w += 256) {
            int jj  = w / 100;
            int rem = w - jj * 100;
            int rr  = rem / 5;
            int q   = rem - rr * 5;
            const vf4 v = *reinterpret_cast<const vf4*>(
                imb + (size_t)rr * SLEN + jj * 4 + q * 4);
            base[(size_t)jj * 200 + rem] = v;
        }
    } else {
        // ---------------- per-tile catalog ----------------
        const int sub = (bid - TILE_BLOCKS) * 256 + tid;
        if (sub >= NSUB) return;

        const int b = sub / NPT;
        const int t = sub % NPT;
        const int i = t / N1;
        const int j = t % N1;

        const float lox = (float)(i * STEP) + 1.5f;   // tc.x + EP - 0.5
        const float loy = (float)(j * STEP) + 1.5f;
        const float hix = lox + 16.0f;                // tc - 0.5 + PT - EP
        const float hiy = loy + 16.0f;

        int   cnt = 0;
        int   sid[2] = {0, 0};
        float slx[2] = {0.f, 0.f};
        float sly[2] = {0.f, 0.f};

        const float* lb = locs + (size_t)b * NS * 2;
        #pragma unroll
        for (int s = 0; s < NS; ++s) {
            float lx = lb[2 * s + 0] * (float)(SLEN - 1);
            float ly = lb[2 * s + 1] * (float)(SLEN - 1);
            bool on = (lx > lox) && (lx < hix) && (ly > loy) && (ly < hiy);
            if (on) {
                if (cnt < MAXD) { sid[cnt] = s; slx[cnt] = lx; sly[cnt] = ly; }
                cnt++;
            }
        }

        const float inv_scale = 1.0f / 16.0f;  // 1/(PT-2*EP), exact

        float4 lv;
        lv.x = (cnt > 0) ? fmaxf((slx[0] - lox) * inv_scale, 0.0f) : 0.0f;
        lv.y = (cnt > 0) ? fmaxf((sly[0] - loy) * inv_scale, 0.0f) : 0.0f;
        lv.z = (cnt > 1) ? fmaxf((slx[1] - lox) * inv_scale, 0.0f) : 0.0f;
        lv.w = (cnt > 1) ? fmaxf((sly[1] - loy) * inv_scale, 0.0f) : 0.0f;
        reinterpret_cast<float4*>(out + OFF_LOCS)[sub] = lv;

        float4 g0 = {0,0,0,0}, g1 = {0,0,0,0}, g2 = {0,0,0,0}, g3 = {0,0,0,0};
        if (cnt > 0) {
            const float4* gp = reinterpret_cast<const float4*>(
                gal + ((size_t)(b * NS + sid[0])) * NGAL);
            g0 = gp[0]; g1 = gp[1];
        }
        if (cnt > 1) {
            const float4* gp = reinterpret_cast<const float4*>(
                gal + ((size_t)(b * NS + sid[1])) * NGAL);
            g2 = gp[0]; g3 = gp[1];
        }
        float4* go = reinterpret_cast<float4*>(out + OFF_GAL) + (size_t)sub * 4;
        go[0] = g0; go[1] = g1; go[2] = g2; go[3] = g3;

        float4 fv = {0,0,0,0};
        if (cnt > 0) {
            const float2 f = reinterpret_cast<const float2*>(
                flux + ((size_t)(b * NS + sid[0])) * NBANDS)[0];
            fv.x = f.x; fv.y = f.y;
        }
        if (cnt > 1) {
            const float2 f = reinterpret_cast<const float2*>(
                flux + ((size_t)(b * NS + sid[1])) * NBANDS)[0];
            fv.z = f.x; fv.w = f.y;
        }
        reinterpret_cast<float4*>(out + OFF_FLUX)[sub] = fv;

        out[OFF_N + sub] = (float)(cnt < MAXD ? cnt : MAXD);
        float2 ison;
        ison.x = (cnt > 0) ? 1.0f : 0.0f;
        ison.y = (cnt > 1) ? 1.0f : 0.0f;
        reinterpret_cast<float2*>(out + OFF_ISON)[sub] = ison;
    }
}

extern "C" void kernel_launch(void* const* d_in, const int* in_sizes, int n_in,
                              void* d_out, int out_size, void* d_ws, size_t ws_size,
                              hipStream_t stream)
{
    const float* images = (const float*)d_in[0];
    const float* locs   = (const float*)d_in[1];
    const float* gal    = (const float*)d_in[2];
    const float* flux   = (const float*)d_in[3];
    float* out = (float*)d_out;

    fused_kernel<<<TILE_BLOCKS + CAT_BLOCKS, 256, 0, stream>>>(
        images, locs, gal, flux, out);
}